// Round 9
// baseline (338.759 us; speedup 1.0000x reference)
//
#include <hip/hip_runtime.h>
#include <math.h>

#define A_CUBIC (-0.75f)
#define NB 2
#define NC 3
#define HH 144
#define NPB 2304      // patches per batch (48*48)
#define GG 14460      // database patches per batch
#define DD 27
#define DP 28         // padded row stride; row[27] holds gn (for gf) or -1 (for m)
#define GSPLIT 337
#define GTILE 43      // 337*43 = 14491 >= 14460

__constant__ int c_seg_start[15] = {0,2209,2738,2859,5068,5597,5718,7927,8456,8577,10786,11315,11436,13740,14316};
__constant__ int c_seg_gw[15]    = {47,23,11, 47,23,11, 47,23,11, 47,23,11, 48,24,12};
__constant__ int c_seg_oy[15]    = {1,1,1, 1,1,1, 2,2,2, 2,2,2, 0,0,0};
__constant__ int c_seg_ox[15]    = {1,1,1, 2,2,2, 1,1,1, 2,2,2, 0,0,0};
__constant__ int c_seg_src[15]   = {0,1,2, 0,1,2, 0,1,2, 0,1,2, 0,1,2};

__device__ __forceinline__ float cubicw(float t) {
    float at = fabsf(t);
    if (at <= 1.0f) return ((A_CUBIC + 2.0f) * at - (A_CUBIC + 3.0f)) * at * at + 1.0f;
    if (at < 2.0f)  return A_CUBIC * (((at - 5.0f) * at + 8.0f) * at - 4.0f);
    return 0.0f;
}

// K1: bicubic downscale tar -> s1 (72x72), s2 (36x36), PLUS m-row build + best init.
__global__ void prep_k(const float* __restrict__ tar, const float* __restrict__ inp,
                       float* __restrict__ s1, float* __restrict__ s2,
                       float* __restrict__ m, unsigned long long* __restrict__ best) {
    int t = blockIdx.x * 256 + threadIdx.x;
    const int total1 = NB * NC * 72 * 72;
    const int total2 = NB * NC * 36 * 36;
    if (t < total1 + total2) {
        float* dst; int O; int idx;
        if (t < total1) { dst = s1; O = 72; idx = t; }
        else            { dst = s2; O = 36; idx = t - total1; }
        int x  = idx % O;
        int y  = (idx / O) % O;
        int bc = idx / (O * O);
        const float* src = tar + (size_t)bc * HH * HH;
        float scale = (float)(143.0 / (double)(O - 1));
        float fy = (float)y * scale;
        float iyf = floorf(fy); float fry = fy - iyf; int iy = (int)iyf;
        float fx = (float)x * scale;
        float ixf = floorf(fx); float frx = fx - ixf; int ix = (int)ixf;
        float wy[4], wx[4];
        #pragma unroll
        for (int d = 0; d < 4; ++d) {
            wy[d] = cubicw(fry - (float)(d - 1));
            wx[d] = cubicw(frx - (float)(d - 1));
        }
        float acc = 0.0f;
        #pragma unroll
        for (int dx = 0; dx < 4; ++dx) {
            int cx = min(max(ix - 1 + dx, 0), HH - 1);
            float inner = 0.0f;
            #pragma unroll
            for (int dy = 0; dy < 4; ++dy) {
                int cy = min(max(iy - 1 + dy, 0), HH - 1);
                inner += wy[dy] * src[cy * HH + cx];
            }
            acc += wx[dx] * inner;
        }
        dst[idx] = acc;
    } else {
        int u = t - (total1 + total2);
        if (u >= NB * NPB) return;
        int b = u / NPB, n = u % NPB;
        int hc = n / 48, wc = n % 48;
        const float* ib = inp + (size_t)b * NC * HH * HH;
        const float* tb = tar + (size_t)b * NC * HH * HH;
        float* row = m + (size_t)u * DP;
        #pragma unroll
        for (int c = 0; c < 3; ++c)
            #pragma unroll
            for (int dy = 0; dy < 3; ++dy)
                #pragma unroll
                for (int dx = 0; dx < 3; ++dx) {
                    int off = (c * HH + hc * 3 + dy) * HH + wc * 3 + dx;
                    row[(c * 3 + dy) * 3 + dx] = ib[off] + tb[off];
                }
        row[27] = -1.0f;
        best[u] = 0ULL;
    }
}

// K2: build gf database rows [B*G][28]; row[27] = |g|^2
__global__ void build_gf_k(const float* __restrict__ tar, const float* __restrict__ s1,
                           const float* __restrict__ s2, float* __restrict__ gf) {
    int t = blockIdx.x * 256 + threadIdx.x;
    if (t >= NB * GG) return;
    int b = t / GG, g = t % GG;
    int s = 0;
    #pragma unroll
    for (int k = 1; k < 15; ++k) if (g >= c_seg_start[k]) s = k;
    int p  = g - c_seg_start[s];
    int gw = c_seg_gw[s];
    int hc = p / gw, wc = p % gw;
    int oy = c_seg_oy[s], ox = c_seg_ox[s];
    int srci = c_seg_src[s];
    const float* img; int sz;
    if (srci == 0)      { img = tar; sz = 144; }
    else if (srci == 1) { img = s1;  sz = 72;  }
    else                { img = s2;  sz = 36;  }
    const float* base = img + (size_t)b * NC * sz * sz;
    int y0 = oy + hc * 3, x0 = ox + wc * 3;
    float acc = 0.0f;
    float* row = gf + (size_t)t * DP;
    #pragma unroll
    for (int c = 0; c < 3; ++c)
        #pragma unroll
        for (int dy = 0; dy < 3; ++dy)
            #pragma unroll
            for (int dx = 0; dx < 3; ++dx) {
                float v = base[((size_t)c * sz + y0 + dy) * sz + x0 + dx];
                row[(c * 3 + dy) * 3 + dx] = v;
                acc = fmaf(v, v, acc);
            }
    row[27] = acc;
}

// K4: 3 n-rows per thread (LDS-staged -> resident mr[3][7]); g-rows streamed via
// per-lane global_load_dwordx4 at a uniform address (opaque-zero defeats the
// scalarizer) -> broadcast L1 hits, vmcnt-pipelined ping-pong. No launch bound:
// VGPR cap 256 so nothing is demoted.
__global__ void argmin_k(const float* __restrict__ gf, const float* __restrict__ m,
                         unsigned long long* __restrict__ best) {
    __shared__ __align__(16) float mlds[256 * DP];   // 28 KB
    int tid = threadIdx.x;
    int nb = blockIdx.y;                // 0..5 (768 n each)
    int b  = nb / 3;
    int n0 = nb * 768 + tid;            // owns n0, n0+256, n0+512

    float4 mr[3][7];
    #pragma unroll
    for (int c = 0; c < 3; ++c) {
        const float4* src = (const float4*)(m + ((size_t)nb * 768 + c * 256) * DP);
        float4* dst = (float4*)mlds;
        #pragma unroll
        for (int k = 0; k < 7; ++k) dst[tid + k * 256] = src[tid + k * 256];
        __syncthreads();
        #pragma unroll
        for (int i = 0; i < 7; ++i) mr[c][i] = *(const float4*)&mlds[tid * DP + i * 4];
        __syncthreads();
    }

    int g0 = blockIdx.x * GTILE;
    int g1 = min(g0 + GTILE, GG);
    if (g0 >= g1) return;

    // opaque zero: prevents the compiler proving the g address wave-uniform,
    // forcing vector global_load (broadcast) instead of out-of-order s_load.
    int zero;
    asm volatile("v_mov_b32 %0, 0" : "=v"(zero));
    const float4* gp = (const float4*)(gf + (size_t)b * GG * DP + zero) + (size_t)g0 * 7;

    float bv0 = -3.0e38f, bv1 = -3.0e38f, bv2 = -3.0e38f;
    int   bi0 = 0,        bi1 = 0,        bi2 = 0;

    float4 A[7], B[7];
    #pragma unroll
    for (int i = 0; i < 7; ++i) A[i] = gp[i];
    gp += 7;

#define DOT3(R, S0, S1, S2)                                                   \
    {                                                                         \
        float a00, a01, a02, a03, a10, a11, a12, a13, a20, a21, a22, a23;     \
        a00 = mr[0][0].x * R[0].x; a01 = mr[0][0].y * R[0].y;                 \
        a02 = mr[0][0].z * R[0].z; a03 = mr[0][0].w * R[0].w;                 \
        a10 = mr[1][0].x * R[0].x; a11 = mr[1][0].y * R[0].y;                 \
        a12 = mr[1][0].z * R[0].z; a13 = mr[1][0].w * R[0].w;                 \
        a20 = mr[2][0].x * R[0].x; a21 = mr[2][0].y * R[0].y;                 \
        a22 = mr[2][0].z * R[0].z; a23 = mr[2][0].w * R[0].w;                 \
        _Pragma("unroll")                                                     \
        for (int i = 1; i < 7; ++i) {                                         \
            a00 = fmaf(mr[0][i].x, R[i].x, a00);                              \
            a01 = fmaf(mr[0][i].y, R[i].y, a01);                              \
            a02 = fmaf(mr[0][i].z, R[i].z, a02);                              \
            a03 = fmaf(mr[0][i].w, R[i].w, a03);                              \
            a10 = fmaf(mr[1][i].x, R[i].x, a10);                              \
            a11 = fmaf(mr[1][i].y, R[i].y, a11);                              \
            a12 = fmaf(mr[1][i].z, R[i].z, a12);                              \
            a13 = fmaf(mr[1][i].w, R[i].w, a13);                              \
            a20 = fmaf(mr[2][i].x, R[i].x, a20);                              \
            a21 = fmaf(mr[2][i].y, R[i].y, a21);                              \
            a22 = fmaf(mr[2][i].z, R[i].z, a22);                              \
            a23 = fmaf(mr[2][i].w, R[i].w, a23);                              \
        }                                                                     \
        S0 = (a00 + a01) + (a02 + a03);                                       \
        S1 = (a10 + a11) + (a12 + a13);                                       \
        S2 = (a20 + a21) + (a22 + a23);                                       \
    }

    int g = g0;
    for (; g + 1 < g1; g += 2) {
        #pragma unroll
        for (int i = 0; i < 7; ++i) B[i] = gp[i];      // prefetch row g+1
        gp += 7;
        float s0, s1, s2;
        DOT3(A, s0, s1, s2);
        if (s0 > bv0) { bv0 = s0; bi0 = g; }           // strict >: first max kept
        if (s1 > bv1) { bv1 = s1; bi1 = g; }
        if (s2 > bv2) { bv2 = s2; bi2 = g; }
        #pragma unroll
        for (int i = 0; i < 7; ++i) A[i] = gp[i];      // prefetch row g+2 (<=1 row overread)
        gp += 7;
        DOT3(B, s0, s1, s2);
        if (s0 > bv0) { bv0 = s0; bi0 = g + 1; }
        if (s1 > bv1) { bv1 = s1; bi1 = g + 1; }
        if (s2 > bv2) { bv2 = s2; bi2 = g + 1; }
    }
    if (g < g1) {
        float s0, s1, s2;
        DOT3(A, s0, s1, s2);
        if (s0 > bv0) { bv0 = s0; bi0 = g; }
        if (s1 > bv1) { bv1 = s1; bi1 = g; }
        if (s2 > bv2) { bv2 = s2; bi2 = g; }
    }
#undef DOT3
    // monotonic float encoding; low word ~g so equal scores prefer smaller g
    unsigned u0 = __float_as_uint(bv0); u0 ^= (unsigned)(((int)u0 >> 31)) | 0x80000000u;
    unsigned u1 = __float_as_uint(bv1); u1 ^= (unsigned)(((int)u1 >> 31)) | 0x80000000u;
    unsigned u2 = __float_as_uint(bv2); u2 ^= (unsigned)(((int)u2 >> 31)) | 0x80000000u;
    atomicMax(&best[n0],       ((unsigned long long)u0 << 32) | (unsigned)(~bi0));
    atomicMax(&best[n0 + 256], ((unsigned long long)u1 << 32) | (unsigned)(~bi1));
    atomicMax(&best[n0 + 512], ((unsigned long long)u2 << 32) | (unsigned)(~bi2));
}

// K5: decode best, gather sel, fold to image, block-partial L1 sums
__global__ void finalize_k(const float* __restrict__ gf,
                           const unsigned long long* __restrict__ best,
                           const float* __restrict__ inp,
                           float* __restrict__ out, float* __restrict__ lpart) {
    __shared__ float red[256];
    int t = blockIdx.x * 256 + threadIdx.x;
    float lsum = 0.0f;
    if (t < NB * NPB) {
        int b = t / NPB, n = t % NPB;
        unsigned long long pk = best[t];
        int bi = (int)(~(unsigned)(pk & 0xFFFFFFFFull));
        int hc = n / 48, wc = n % 48;
        const float* grow = gf + ((size_t)b * GG + bi) * DP;
        const float* ib   = inp + (size_t)b * NC * HH * HH;
        float* sel = out + 1 + (size_t)b * NC * HH * HH;
        #pragma unroll
        for (int c = 0; c < 3; ++c)
            #pragma unroll
            for (int dy = 0; dy < 3; ++dy)
                #pragma unroll
                for (int dx = 0; dx < 3; ++dx) {
                    int d = (c * 3 + dy) * 3 + dx;
                    float sv = grow[d];
                    int off = (c * HH + hc * 3 + dy) * HH + wc * 3 + dx;
                    sel[off] = sv;
                    lsum += fabsf(ib[off] - sv);
                }
    }
    red[threadIdx.x] = lsum;
    __syncthreads();
    for (int s = 128; s > 0; s >>= 1) {
        if (threadIdx.x < s) red[threadIdx.x] += red[threadIdx.x + s];
        __syncthreads();
    }
    if (threadIdx.x == 0) lpart[blockIdx.x] = red[0];
}

// K6: scalar loss mean
__global__ void sum_k(const float* __restrict__ lpart, float* __restrict__ out) {
    if (threadIdx.x == 0) {
        float s = 0.0f;
        for (int i = 0; i < 18; ++i) s += lpart[i];
        out[0] = s * (1.0f / 124416.0f);
    }
}

extern "C" void kernel_launch(void* const* d_in, const int* in_sizes, int n_in,
                              void* d_out, int out_size, void* d_ws, size_t ws_size,
                              hipStream_t stream) {
    const float* inp = (const float*)d_in[0];
    const float* tar = (const float*)d_in[1];
    float* out = (float*)d_out;
    float* ws  = (float*)d_ws;

    float* s1 = ws;                       // 31104
    float* s2 = s1 + 31104;               // 7776
    float* gf = s2 + 7776;                // 2*14460*28 = 809760
    float* m  = gf + 809760;              // 2*2304*28 = 129024
    unsigned long long* best = (unsigned long long*)(m + 129024);  // 4608 u64
    float* lp = (float*)(best + 4608);    // 18

    prep_k    <<<(43488 + 255) / 256, 256, 0, stream>>>(tar, inp, s1, s2, m, best);
    build_gf_k<<<(28920 + 255) / 256, 256, 0, stream>>>(tar, s1, s2, gf);
    argmin_k  <<<dim3(GSPLIT, 6), 256, 0, stream>>>(gf, m, best);
    finalize_k<<<18, 256, 0, stream>>>(gf, best, inp, out, lp);
    sum_k     <<<1, 64, 0, stream>>>(lp, out);
}

// Round 10
// 74.471 us; speedup vs baseline: 4.5489x; 4.5489x over previous
//
#include <hip/hip_runtime.h>
#include <math.h>

#define A_CUBIC (-0.75f)
#define NB 2
#define NC 3
#define HH 144
#define NPB 2304      // patches per batch (48*48)
#define GG 14460      // database patches per batch
#define DD 27
#define DP 28         // padded row stride; row[27] holds gn (for gf) or -1 (for m)
#define GSPLIT 256
#define GTILE 57      // 256*57 = 14592 >= 14460

__constant__ int c_seg_start[15] = {0,2209,2738,2859,5068,5597,5718,7927,8456,8577,10786,11315,11436,13740,14316};
__constant__ int c_seg_gw[15]    = {47,23,11, 47,23,11, 47,23,11, 47,23,11, 48,24,12};
__constant__ int c_seg_oy[15]    = {1,1,1, 1,1,1, 2,2,2, 2,2,2, 0,0,0};
__constant__ int c_seg_ox[15]    = {1,1,1, 2,2,2, 1,1,1, 2,2,2, 0,0,0};
__constant__ int c_seg_src[15]   = {0,1,2, 0,1,2, 0,1,2, 0,1,2, 0,1,2};

__device__ __forceinline__ float cubicw(float t) {
    float at = fabsf(t);
    if (at <= 1.0f) return ((A_CUBIC + 2.0f) * at - (A_CUBIC + 3.0f)) * at * at + 1.0f;
    if (at < 2.0f)  return A_CUBIC * (((at - 5.0f) * at + 8.0f) * at - 4.0f);
    return 0.0f;
}

// K1: bicubic downscale tar -> s1 (72x72), s2 (36x36), PLUS m-row build + best init.
__global__ void prep_k(const float* __restrict__ tar, const float* __restrict__ inp,
                       float* __restrict__ s1, float* __restrict__ s2,
                       float* __restrict__ m, unsigned long long* __restrict__ best) {
    int t = blockIdx.x * 256 + threadIdx.x;
    const int total1 = NB * NC * 72 * 72;
    const int total2 = NB * NC * 36 * 36;
    if (t < total1 + total2) {
        float* dst; int O; int idx;
        if (t < total1) { dst = s1; O = 72; idx = t; }
        else            { dst = s2; O = 36; idx = t - total1; }
        int x  = idx % O;
        int y  = (idx / O) % O;
        int bc = idx / (O * O);
        const float* src = tar + (size_t)bc * HH * HH;
        float scale = (float)(143.0 / (double)(O - 1));
        float fy = (float)y * scale;
        float iyf = floorf(fy); float fry = fy - iyf; int iy = (int)iyf;
        float fx = (float)x * scale;
        float ixf = floorf(fx); float frx = fx - ixf; int ix = (int)ixf;
        float wy[4], wx[4];
        #pragma unroll
        for (int d = 0; d < 4; ++d) {
            wy[d] = cubicw(fry - (float)(d - 1));
            wx[d] = cubicw(frx - (float)(d - 1));
        }
        float acc = 0.0f;
        #pragma unroll
        for (int dx = 0; dx < 4; ++dx) {
            int cx = min(max(ix - 1 + dx, 0), HH - 1);
            float inner = 0.0f;
            #pragma unroll
            for (int dy = 0; dy < 4; ++dy) {
                int cy = min(max(iy - 1 + dy, 0), HH - 1);
                inner += wy[dy] * src[cy * HH + cx];
            }
            acc += wx[dx] * inner;
        }
        dst[idx] = acc;
    } else {
        int u = t - (total1 + total2);
        if (u >= NB * NPB) return;
        int b = u / NPB, n = u % NPB;
        int hc = n / 48, wc = n % 48;
        const float* ib = inp + (size_t)b * NC * HH * HH;
        const float* tb = tar + (size_t)b * NC * HH * HH;
        float* row = m + (size_t)u * DP;
        #pragma unroll
        for (int c = 0; c < 3; ++c)
            #pragma unroll
            for (int dy = 0; dy < 3; ++dy)
                #pragma unroll
                for (int dx = 0; dx < 3; ++dx) {
                    int off = (c * HH + hc * 3 + dy) * HH + wc * 3 + dx;
                    row[(c * 3 + dy) * 3 + dx] = ib[off] + tb[off];
                }
        row[27] = -1.0f;
        best[u] = 0ULL;
    }
}

// K2: build gf database rows [B*G][28]; row[27] = |g|^2
__global__ void build_gf_k(const float* __restrict__ tar, const float* __restrict__ s1,
                           const float* __restrict__ s2, float* __restrict__ gf) {
    int t = blockIdx.x * 256 + threadIdx.x;
    if (t >= NB * GG) return;
    int b = t / GG, g = t % GG;
    int s = 0;
    #pragma unroll
    for (int k = 1; k < 15; ++k) if (g >= c_seg_start[k]) s = k;
    int p  = g - c_seg_start[s];
    int gw = c_seg_gw[s];
    int hc = p / gw, wc = p % gw;
    int oy = c_seg_oy[s], ox = c_seg_ox[s];
    int srci = c_seg_src[s];
    const float* img; int sz;
    if (srci == 0)      { img = tar; sz = 144; }
    else if (srci == 1) { img = s1;  sz = 72;  }
    else                { img = s2;  sz = 36;  }
    const float* base = img + (size_t)b * NC * sz * sz;
    int y0 = oy + hc * 3, x0 = ox + wc * 3;
    float acc = 0.0f;
    float* row = gf + (size_t)t * DP;
    #pragma unroll
    for (int c = 0; c < 3; ++c)
        #pragma unroll
        for (int dy = 0; dy < 3; ++dy)
            #pragma unroll
            for (int dx = 0; dx < 3; ++dx) {
                float v = base[((size_t)c * sz + y0 + dy) * sz + x0 + dx];
                row[(c * 3 + dy) * 3 + dx] = v;
                acc = fmaf(v, v, acc);
            }
    row[27] = acc;
}

// K4: 3 n-rows per thread; m loaded once from global (float4) — residency
// enabled by amdgpu_waves_per_eu(1,4) raising the allocator's register budget
// to 128. g-tile (57 rows, 6.4 KB) staged coalesced into LDS once per block,
// then read as wave-uniform BROADCAST ds_read_b128 (proven 7.8 cyc, R2).
// NO per-lane loads of uniform addresses (R9 lesson: TA doesn't merge them).
__global__ __launch_bounds__(256) __attribute__((amdgpu_waves_per_eu(1, 4)))
void argmin_k(const float* __restrict__ gf, const float* __restrict__ m,
              unsigned long long* __restrict__ best) {
    __shared__ __align__(16) float glds[GTILE * DP];   // 6384 B
    int tid = threadIdx.x;
    int nb = blockIdx.y;                // 0..5 (768 n each; 3 per batch)
    int b  = nb / 3;
    int n0 = nb * 768 + tid;            // owns n0, n0+256, n0+512

    float4 mr0[7], mr1[7], mr2[7];
    {
        const float4* p0 = (const float4*)(m + (size_t)n0 * DP);
        const float4* p1 = (const float4*)(m + (size_t)(n0 + 256) * DP);
        const float4* p2 = (const float4*)(m + (size_t)(n0 + 512) * DP);
        #pragma unroll
        for (int i = 0; i < 7; ++i) { mr0[i] = p0[i]; mr1[i] = p1[i]; mr2[i] = p2[i]; }
    }

    int g0 = blockIdx.x * GTILE;
    int g1 = min(g0 + GTILE, GG);
    int nload = g1 - g0; if (nload < 0) nload = 0;

    {   // coalesced stage: nload*7 float4s
        const float4* src = (const float4*)(gf + ((size_t)b * GG + g0) * DP);
        float4* dst = (float4*)glds;
        for (int k = tid; k < nload * 7; k += 256) dst[k] = src[k];
    }
    __syncthreads();

    float bv0 = -3.0e38f, bv1 = -3.0e38f, bv2 = -3.0e38f;
    int   bi0 = 0,        bi1 = 0,        bi2 = 0;

    for (int j = 0; j < nload; ++j) {
        const float4* gr = (const float4*)&glds[j * DP];   // uniform -> broadcast
        float a00, a01, a02, a03, a10, a11, a12, a13, a20, a21, a22, a23;
        float4 gv = gr[0];
        a00 = mr0[0].x * gv.x; a01 = mr0[0].y * gv.y; a02 = mr0[0].z * gv.z; a03 = mr0[0].w * gv.w;
        a10 = mr1[0].x * gv.x; a11 = mr1[0].y * gv.y; a12 = mr1[0].z * gv.z; a13 = mr1[0].w * gv.w;
        a20 = mr2[0].x * gv.x; a21 = mr2[0].y * gv.y; a22 = mr2[0].z * gv.z; a23 = mr2[0].w * gv.w;
        #pragma unroll
        for (int i = 1; i < 7; ++i) {
            gv = gr[i];
            a00 = fmaf(mr0[i].x, gv.x, a00); a01 = fmaf(mr0[i].y, gv.y, a01);
            a02 = fmaf(mr0[i].z, gv.z, a02); a03 = fmaf(mr0[i].w, gv.w, a03);
            a10 = fmaf(mr1[i].x, gv.x, a10); a11 = fmaf(mr1[i].y, gv.y, a11);
            a12 = fmaf(mr1[i].z, gv.z, a12); a13 = fmaf(mr1[i].w, gv.w, a13);
            a20 = fmaf(mr2[i].x, gv.x, a20); a21 = fmaf(mr2[i].y, gv.y, a21);
            a22 = fmaf(mr2[i].z, gv.z, a22); a23 = fmaf(mr2[i].w, gv.w, a23);
        }
        float s0 = (a00 + a01) + (a02 + a03);
        float s1 = (a10 + a11) + (a12 + a13);
        float s2 = (a20 + a21) + (a22 + a23);
        int gg = g0 + j;
        if (s0 > bv0) { bv0 = s0; bi0 = gg; }   // strict >: keeps first max
        if (s1 > bv1) { bv1 = s1; bi1 = gg; }
        if (s2 > bv2) { bv2 = s2; bi2 = gg; }
    }
    if (nload > 0) {
        unsigned u0 = __float_as_uint(bv0); u0 ^= (unsigned)(((int)u0 >> 31)) | 0x80000000u;
        unsigned u1 = __float_as_uint(bv1); u1 ^= (unsigned)(((int)u1 >> 31)) | 0x80000000u;
        unsigned u2 = __float_as_uint(bv2); u2 ^= (unsigned)(((int)u2 >> 31)) | 0x80000000u;
        atomicMax(&best[n0],       ((unsigned long long)u0 << 32) | (unsigned)(~bi0));
        atomicMax(&best[n0 + 256], ((unsigned long long)u1 << 32) | (unsigned)(~bi1));
        atomicMax(&best[n0 + 512], ((unsigned long long)u2 << 32) | (unsigned)(~bi2));
    }
}

// K5: decode best, gather sel, fold to image, block-partial L1 sums
__global__ void finalize_k(const float* __restrict__ gf,
                           const unsigned long long* __restrict__ best,
                           const float* __restrict__ inp,
                           float* __restrict__ out, float* __restrict__ lpart) {
    __shared__ float red[256];
    int t = blockIdx.x * 256 + threadIdx.x;
    float lsum = 0.0f;
    if (t < NB * NPB) {
        int b = t / NPB, n = t % NPB;
        unsigned long long pk = best[t];
        int bi = (int)(~(unsigned)(pk & 0xFFFFFFFFull));
        int hc = n / 48, wc = n % 48;
        const float* grow = gf + ((size_t)b * GG + bi) * DP;
        const float* ib   = inp + (size_t)b * NC * HH * HH;
        float* sel = out + 1 + (size_t)b * NC * HH * HH;
        #pragma unroll
        for (int c = 0; c < 3; ++c)
            #pragma unroll
            for (int dy = 0; dy < 3; ++dy)
                #pragma unroll
                for (int dx = 0; dx < 3; ++dx) {
                    int d = (c * 3 + dy) * 3 + dx;
                    float sv = grow[d];
                    int off = (c * HH + hc * 3 + dy) * HH + wc * 3 + dx;
                    sel[off] = sv;
                    lsum += fabsf(ib[off] - sv);
                }
    }
    red[threadIdx.x] = lsum;
    __syncthreads();
    for (int s = 128; s > 0; s >>= 1) {
        if (threadIdx.x < s) red[threadIdx.x] += red[threadIdx.x + s];
        __syncthreads();
    }
    if (threadIdx.x == 0) lpart[blockIdx.x] = red[0];
}

// K6: scalar loss mean
__global__ void sum_k(const float* __restrict__ lpart, float* __restrict__ out) {
    if (threadIdx.x == 0) {
        float s = 0.0f;
        for (int i = 0; i < 18; ++i) s += lpart[i];
        out[0] = s * (1.0f / 124416.0f);
    }
}

extern "C" void kernel_launch(void* const* d_in, const int* in_sizes, int n_in,
                              void* d_out, int out_size, void* d_ws, size_t ws_size,
                              hipStream_t stream) {
    const float* inp = (const float*)d_in[0];
    const float* tar = (const float*)d_in[1];
    float* out = (float*)d_out;
    float* ws  = (float*)d_ws;

    float* s1 = ws;                       // 31104
    float* s2 = s1 + 31104;               // 7776
    float* gf = s2 + 7776;                // 2*14460*28 = 809760
    float* m  = gf + 809760;              // 2*2304*28 = 129024
    unsigned long long* best = (unsigned long long*)(m + 129024);  // 4608 u64
    float* lp = (float*)(best + 4608);    // 18

    prep_k    <<<(43488 + 255) / 256, 256, 0, stream>>>(tar, inp, s1, s2, m, best);
    build_gf_k<<<(28920 + 255) / 256, 256, 0, stream>>>(tar, s1, s2, gf);
    argmin_k  <<<dim3(GSPLIT, 6), 256, 0, stream>>>(gf, m, best);
    finalize_k<<<18, 256, 0, stream>>>(gf, best, inp, out, lp);
    sum_k     <<<1, 64, 0, stream>>>(lp, out);
}